// Round 19
// baseline (52593.530 us; speedup 1.0000x reference)
//
#include <hip/hip_runtime.h>
#include <hip/hip_bf16.h>

#define B_SZ 1024
#define T_SZ 128
#define D_SZ 256
#define H_SZ 512
#define NBLK 64    // one block per 16-row strip: zero inter-block sync
#define NTHR 512

typedef __attribute__((ext_vector_type(8))) short short8;
typedef __attribute__((ext_vector_type(4))) float f32x4;

__device__ inline f32x4 mfma16(short8 a, short8 b, f32x4 c) {
  return __builtin_amdgcn_mfma_f32_16x16x32_bf16(a, b, c, 0, 0, 0);
}

__device__ __forceinline__ unsigned short bfu(float v) {
  union { __hip_bfloat16 b; unsigned short u; } cv;
  cv.b = __float2bfloat16(v);
  return cv.u;
}

// LDS tile format: tile = 16 rows x 64 cols bf16 (1024 ushort, 2 KB); within
// a row, 16B slot s holds k-slot s^(row&7) (bank-conflict swizzle).
__device__ __forceinline__ short8 ldt(const unsigned short* buf, int tile,
                                      int row, int slot) {
  int idx = (tile << 10) + (row << 6) + ((slot ^ (row & 7)) << 3);
  return *(const short8*)(buf + idx);
}
__device__ __forceinline__ void st16(unsigned short* buf, int row, int col, float v) {
  int tile = col >> 6, kc = col & 63;
  int idx = (tile << 10) + (row << 6) + ((((kc >> 3)) ^ (row & 7)) << 3) + (kc & 7);
  buf[idx] = bfu(v);
}

__global__ __launch_bounds__(512, 1) void k_fused(
    const float* __restrict__ xg, const float* __restrict__ xtime,
    const __hip_bfloat16* __restrict__ W1t, const float* __restrict__ b1,
    const __hip_bfloat16* __restrict__ W2t, const float* __restrict__ b2,
    const __hip_bfloat16* __restrict__ Wzrt, const float* __restrict__ bz,
    const float* __restrict__ br, const __hip_bfloat16* __restrict__ Wnt,
    const float* __restrict__ bn, float* __restrict__ hf,
    float* __restrict__ hstdf) {
  // all recurrent state is block-private: LDS bf16 K-dim panels + f32 regs
  __shared__ __align__(16) unsigned short hbf_l[8 * 1024];   // h      16 KB
  __shared__ __align__(16) unsigned short ubf_l[8 * 1024];   // U      16 KB
  __shared__ __align__(16) unsigned short hode_l[8 * 1024];  // h_ode  16 KB
  __shared__ __align__(16) unsigned short hstd_l[8 * 1024];  // hstd   16 KB
  __shared__ __align__(16) unsigned short xl[4 * 1024];      // x      8 KB
  __shared__ __align__(16) unsigned short a4_l[16 * 1024];   // A4     32 KB
  int tid = threadIdx.x, lane = tid & 63, wv = tid >> 6;
  int lr = lane & 15, lg = lane >> 4;
  int m0 = blockIdx.x << 4;        // 16-row strip
  int wb = wv << 6;                // wave's 64-col range (all phases)
  // thread's owned cells: rows (lg*4+r), cols wb + n*16 + lr  (n=0..3)
  float hreg[4][4], sreg[4][4], oreg[4][4], zreg[4][4];
#pragma unroll
  for (int n = 0; n < 4; ++n)
#pragma unroll
    for (int r = 0; r < 4; ++r) { hreg[n][r] = 0.f; sreg[n][r] = 0.f; }

  // zero h/hstd LDS panels (h0 = std0 = 0)
  for (int idx = tid; idx < 8 * 1024; idx += NTHR) { hbf_l[idx] = 0; hstd_l[idx] = 0; }

  // B base pointers (lane-resolved; weights immutable -> L1/L2 cached loads)
  const __hip_bfloat16* w1b = W1t + (size_t)(wb + lr) * H_SZ + (lg << 3);
  const __hip_bfloat16* w2b = W2t + (size_t)(wb + lr) * H_SZ + (lg << 3);
  const __hip_bfloat16* wzb = Wzrt + (size_t)(wb + lr) * 1280 + (lg << 3);
  const __hip_bfloat16* wrb = Wzrt + (size_t)(512 + wb + lr) * 1280 + (lg << 3);
  const __hip_bfloat16* wmb = Wnt + (size_t)(wb + lr) * 1280 + (lg << 3);
  const __hip_bfloat16* wsb = Wnt + (size_t)(512 + wb + lr) * 1280 + (lg << 3);
  // x prefetch addressing: thread loads 8 f32 of x[strip row, t, :]
  int xrow = tid >> 5, xj = tid & 31;        // 16 rows x 32 col-groups
  int xcol0 = xj << 3;
  int xtile = xj >> 3, xslot = xj & 7;
  int xidx = (xtile << 10) + (xrow << 6) + ((xslot ^ (xrow & 7)) << 3);

  __syncthreads();

#pragma unroll 1
  for (int t = 0; t < T_SZ; ++t) {
    // prefetch this step's x slice (consumed in P3; written to LDS at P2 end)
    const float* xp = xg + ((size_t)(m0 + xrow) * T_SZ + t) * D_SZ + xcol0;
    f32x4 xv0 = *(const f32x4*)xp;
    f32x4 xv1 = *(const f32x4*)(xp + 4);
    float dtv = (t == 0) ? 0.01f : (xtime[t] - xtime[t - 1]);
    // ======== P1: U = tanh(h @ W1 + b1) ========
    {
      f32x4 acc[4] = {};
#pragma unroll
      for (int q = 0; q < 8; ++q)
#pragma unroll
        for (int kk = 0; kk < 2; ++kk) {
          short8 a = ldt(hbf_l, q, lr, (kk << 2) + lg);
          int ko = (q << 6) + (kk << 5);
#pragma unroll
          for (int n = 0; n < 4; ++n) {
            short8 bb = *(const short8*)(w1b + (size_t)n * (16 * H_SZ) + ko);
            acc[n] = mfma16(a, bb, acc[n]);
          }
        }
#pragma unroll
      for (int n = 0; n < 4; ++n) {
        int col = wb + (n << 4) + lr;
        float bi = b1[col];
#pragma unroll
        for (int r = 0; r < 4; ++r)
          st16(ubf_l, (lg << 2) + r, col, tanhf(acc[n][r] + bi));
      }
    }
    __syncthreads();
    // ======== P2: h_ode = h + dt*(U @ W2 + b2); x -> LDS ========
    {
      f32x4 acc[4] = {};
#pragma unroll
      for (int q = 0; q < 8; ++q)
#pragma unroll
        for (int kk = 0; kk < 2; ++kk) {
          short8 a = ldt(ubf_l, q, lr, (kk << 2) + lg);
          int ko = (q << 6) + (kk << 5);
#pragma unroll
          for (int n = 0; n < 4; ++n) {
            short8 bb = *(const short8*)(w2b + (size_t)n * (16 * H_SZ) + ko);
            acc[n] = mfma16(a, bb, acc[n]);
          }
        }
#pragma unroll
      for (int n = 0; n < 4; ++n) {
        int col = wb + (n << 4) + lr;
        float bi = b2[col];
#pragma unroll
        for (int r = 0; r < 4; ++r) {
          float v = hreg[n][r] + dtv * (acc[n][r] + bi);
          oreg[n][r] = v;
          st16(hode_l, (lg << 2) + r, col, v);
        }
      }
      // x slice f32 -> bf16 LDS tile (one 16B write per thread)
      short8 xs;
#pragma unroll
      for (int e = 0; e < 4; ++e) {
        xs[e] = (short)bfu(xv0[e]);
        xs[4 + e] = (short)bfu(xv1[e]);
      }
      *(short8*)(xl + xidx) = xs;
    }
    __syncthreads();
    // ======== P3: z,r = sigmoid(cat @ [Wz|Wr]); build A4 in LDS ========
    {
      f32x4 accz[4] = {}, accr[4] = {};
#pragma unroll
      for (int q = 0; q < 20; ++q) {
        const unsigned short* tb;
        int ti;
        if (q < 8)       { tb = hode_l; ti = q; }
        else if (q < 16) { tb = hstd_l; ti = q - 8; }
        else             { tb = xl;     ti = q - 16; }
#pragma unroll
        for (int kk = 0; kk < 2; ++kk) {
          short8 a = ldt(tb, ti, lr, (kk << 2) + lg);
          int ko = (q << 6) + (kk << 5);
#pragma unroll
          for (int n = 0; n < 4; ++n) {
            short8 b0 = *(const short8*)(wzb + (size_t)n * (16 * 1280) + ko);
            short8 b1f = *(const short8*)(wrb + (size_t)n * (16 * 1280) + ko);
            accz[n] = mfma16(a, b0, accz[n]);
            accr[n] = mfma16(a, b1f, accr[n]);
          }
        }
      }
#pragma unroll
      for (int n = 0; n < 4; ++n) {
        int col = wb + (n << 4) + lr;
        float bz_ = bz[col], br_ = br[col];
#pragma unroll
        for (int r = 0; r < 4; ++r) {
          int row = (lg << 2) + r;
          zreg[n][r] = 1.f / (1.f + expf(-(accz[n][r] + bz_)));
          float g = 1.f / (1.f + expf(-(accr[n][r] + br_)));
          st16(a4_l, row, col, oreg[n][r] * g);
          st16(a4_l, row, 512 + col, sreg[n][r] * g);
        }
      }
    }
    __syncthreads();
    // ======== P4: n_mean,n_std; GRU update (regs + LDS panels) ========
    {
      f32x4 accm[4] = {}, accs[4] = {};
#pragma unroll
      for (int q = 0; q < 20; ++q) {
        const unsigned short* tb;
        int ti;
        if (q < 16) { tb = a4_l; ti = q; }
        else        { tb = xl;   ti = q - 16; }
#pragma unroll
        for (int kk = 0; kk < 2; ++kk) {
          short8 a = ldt(tb, ti, lr, (kk << 2) + lg);
          int ko = (q << 6) + (kk << 5);
#pragma unroll
          for (int n = 0; n < 4; ++n) {
            short8 b0 = *(const short8*)(wmb + (size_t)n * (16 * 1280) + ko);
            short8 b1f = *(const short8*)(wsb + (size_t)n * (16 * 1280) + ko);
            accm[n] = mfma16(a, b0, accm[n]);
            accs[n] = mfma16(a, b1f, accs[n]);
          }
        }
      }
#pragma unroll
      for (int n = 0; n < 4; ++n) {
        int col = wb + (n << 4) + lr;
        float bm = bn[col], bs = bn[512 + col];
#pragma unroll
        for (int r = 0; r < 4; ++r) {
          int row = (lg << 2) + r;
          float z = zreg[n][r];
          float hn = (1.f - z) * (accm[n][r] + bm) + z * oreg[n][r];
          hreg[n][r] = hn;
          st16(hbf_l, row, col, hn);
          float ns = fabsf(accs[n][r] + bs);
          float sn = fabsf((1.f - z) * ns + z * sreg[n][r]);
          sreg[n][r] = sn;
          st16(hstd_l, row, col, sn);
        }
      }
    }
    __syncthreads();
  }
  // final output: register state -> global f32
#pragma unroll
  for (int n = 0; n < 4; ++n) {
    int col = wb + (n << 4) + lr;
#pragma unroll
    for (int r = 0; r < 4; ++r) {
      int row = m0 + (lg << 2) + r;
      hf[(size_t)row * H_SZ + col] = hreg[n][r];
      hstdf[(size_t)row * H_SZ + col] = sreg[n][r];
    }
  }
}

// =============== prep: W[k][n] f32  ->  Wt[n][k] bf16 =====================
__global__ void k_wt(const float* __restrict__ W, __hip_bfloat16* __restrict__ Wt,
                     int K, int N, int ld) {
  size_t i = (size_t)blockIdx.x * 256 + threadIdx.x;
  if (i >= (size_t)K * N) return;
  int n = (int)(i / K), k = (int)(i % K);
  Wt[(size_t)n * ld + k] = __float2bfloat16(W[(size_t)k * N + n]);
}

extern "C" void kernel_launch(void* const* d_in, const int* in_sizes, int n_in,
                              void* d_out, int out_size, void* d_ws, size_t ws_size,
                              hipStream_t stream) {
  const float* x     = (const float*)d_in[0];
  const float* xtime = (const float*)d_in[1];
  const float* W1    = (const float*)d_in[2];
  const float* b1    = (const float*)d_in[3];
  const float* W2    = (const float*)d_in[4];
  const float* b2    = (const float*)d_in[5];
  const float* Wz    = (const float*)d_in[6];
  const float* bz    = (const float*)d_in[7];
  const float* Wr    = (const float*)d_in[8];
  const float* br    = (const float*)d_in[9];
  const float* Wn    = (const float*)d_in[10];
  const float* bn    = (const float*)d_in[11];

  char* p = (char*)d_ws;
  __hip_bfloat16* W1t   = (__hip_bfloat16*)(p + 0);
  __hip_bfloat16* W2t   = (__hip_bfloat16*)(p + 524288);
  __hip_bfloat16* Wzrt  = (__hip_bfloat16*)(p + 1048576);
  __hip_bfloat16* Wnt   = (__hip_bfloat16*)(p + 3670016);
  float*          hf    = (float*)(p + 6291456);
  float*          hstdf = (float*)(p + 8388608);

  k_wt<<<(512 * 512 + 255) / 256, 256, 0, stream>>>(W1, W1t, 512, 512, 512);
  k_wt<<<(512 * 512 + 255) / 256, 256, 0, stream>>>(W2, W2t, 512, 512, 512);
  k_wt<<<(1280 * 512 + 255) / 256, 256, 0, stream>>>(Wz, Wzrt, 1280, 512, 1280);
  k_wt<<<(1280 * 512 + 255) / 256, 256, 0, stream>>>(Wr, Wzrt + (size_t)512 * 1280, 1280, 512, 1280);
  k_wt<<<(1280 * 1024 + 255) / 256, 256, 0, stream>>>(Wn, Wnt, 1280, 1024, 1280);

  // persistent kernel: one block per 16-row strip; the whole recurrence is
  // row-local, so ALL state is block-private (LDS panels + registers) —
  // zero inter-block sync, zero global state traffic
  k_fused<<<NBLK, NTHR, 0, stream>>>(x, xtime, W1t, b1, W2t, b2, Wzrt, bz, br,
                                     Wnt, bn, hf, hstdf);

  hipMemcpyAsync(d_out, hf, 2097152, hipMemcpyDeviceToDevice, stream);
  hipMemcpyAsync((char*)d_out + 2097152, hstdf, 2097152, hipMemcpyDeviceToDevice, stream);
}

// Round 20
// 4980.437 us; speedup vs baseline: 10.5600x; 10.5600x over previous
//
#include <hip/hip_runtime.h>
#include <hip/hip_bf16.h>

#define B_SZ 1024
#define T_SZ 128
#define D_SZ 256
#define H_SZ 512
#define NBLK 256
#define NTHR 512
#define AUXS 0x0   // state loads: PLAIN cached (L1+L2). Coherence comes from
                   // write-through L1 stores -> same-XCD L2, plus an explicit
                   // per-CU L1 invalidate (buffer_inv sc0) after each barrier.

typedef __attribute__((ext_vector_type(8))) short short8;
typedef __attribute__((ext_vector_type(4))) float f32x4;

__device__ inline f32x4 mfma16(short8 a, short8 b, f32x4 c) {
  return __builtin_amdgcn_mfma_f32_16x16x32_bf16(a, b, c, 0, 0, 0);
}

// plain write-back state store: write-through L1 -> lands in this XCD's L2,
// retired by the vmcnt(0) drain before the strip barrier signals.
__device__ inline void st_bf16(__hip_bfloat16* p, float v) {
  union { __hip_bfloat16 b; unsigned short u; } cv;
  cv.b = __float2bfloat16(v);
  unsigned int vv = cv.u;
  asm volatile("global_store_short %0, %1, off" :: "v"(p), "v"(vv) : "memory");
}

// per-CU vector-L1 invalidate (sc0 selects L1 only — NOT the r4 L2-scope
// disaster). Makes subsequent plain loads see the XCD-L2's fresh state.
#define INV()                                        \
  do {                                               \
    asm volatile("buffer_inv sc0" ::: "memory");     \
    __builtin_amdgcn_sched_barrier(0);               \
  } while (0)

// Stage ROWSx64 bf16 tile -> LDS [ROWS][64], slot-swizzled (slot s of row r
// holds k-slot s^(r&7)); linear LDS dest + inverse-swizzled global source.
// 512-thread block: ROWS=32 -> waves 0-3 issue 1 instr; ROWS=64 -> all waves.
template <int ROWS, int AUX>
__device__ __forceinline__ void stage512(const __hip_bfloat16* __restrict__ src,
                                         int strideElts, int row0, int k0,
                                         unsigned short* lds, int tid) {
  constexpr int CH = ROWS * 8;
#pragma unroll
  for (int it = 0; it * NTHR < CH; ++it) {
    int wbase = it * NTHR + ((tid >> 6) << 6);
    if (wbase < CH) {
      int chunk = it * NTHR + tid;
      int row = chunk >> 3, slot = chunk & 7;
      int ksrc = (slot ^ (row & 7)) << 3;
      const __hip_bfloat16* g = src + (size_t)(row0 + row) * strideElts + (k0 + ksrc);
      unsigned short* l = lds + (size_t)wbase * 8;
      __builtin_amdgcn_global_load_lds(
          (const __attribute__((address_space(1))) unsigned int*)g,
          (__attribute__((address_space(3))) unsigned int*)l, 16, 0, AUX);
    }
  }
}

__device__ __forceinline__ short8 ldfrag(const unsigned short* lds, int row, int slot) {
  int s = slot ^ (row & 7);
  return *(const short8*)(lds + row * 64 + s * 8);
}

// Counted-vmcnt mainloop, 8 waves. A depth-4 (5 buffers, waves 0-3 issue, 1
// instr each), B depth-3 (4 buffers, B0..2 prestaged pre-gloop, PB instrs per
// wave per tile). Per-iter order: wait, barrier, sb(kt+3), sa(kt+4), cc(kt).
// In-order vmcnt per wave class:
//  waves 0-3: kt=0 vmcnt(3); kt=1 vmcnt(3+PB); 2..NT-4 vmcnt(3+2PB);
//             NT-3 vmcnt(2+2PB); NT-2 vmcnt(1+PB); NT-1 vmcnt(0)
//  waves 4-7 (B only): <=NT-3 vmcnt(2PB); NT-2 vmcnt(PB); NT-1 vmcnt(0)
template <int NT, int PB, typename SA, typename SB, typename CC>
__device__ __forceinline__ void gloop(int wv, SA sa, SB sb, CC cc) {
  sa(0, 0); sa(1, 1); sa(2, 2); sa(3, 3);   // waves 4-7 no-op internally
#pragma unroll 1
  for (int kt = 0; kt < NT; ++kt) {
    if (wv < 4) {
      if (kt == 0)           asm volatile("s_waitcnt vmcnt(3)" ::: "memory");
      else if (kt == 1)      asm volatile("s_waitcnt vmcnt(%0)" :: "i"(3 + PB) : "memory");
      else if (kt <= NT - 4) asm volatile("s_waitcnt vmcnt(%0)" :: "i"(3 + 2 * PB) : "memory");
      else if (kt == NT - 3) asm volatile("s_waitcnt vmcnt(%0)" :: "i"(2 + 2 * PB) : "memory");
      else if (kt == NT - 2) asm volatile("s_waitcnt vmcnt(%0)" :: "i"(1 + PB) : "memory");
      else                   asm volatile("s_waitcnt vmcnt(0)" ::: "memory");
    } else {
      if (kt <= NT - 3)      asm volatile("s_waitcnt vmcnt(%0)" :: "i"(2 * PB) : "memory");
      else if (kt == NT - 2) asm volatile("s_waitcnt vmcnt(%0)" :: "i"(PB) : "memory");
      else                   asm volatile("s_waitcnt vmcnt(0)" ::: "memory");
    }
    __builtin_amdgcn_s_barrier();
    __builtin_amdgcn_sched_barrier(0);
    if (kt + 3 < NT) sb(kt + 3, (kt + 3) & 3);
    if (kt + 4 < NT) sa(kt + 4, (kt + 4) % 5);
    cc(kt % 5, kt & 3);
  }
}

// Strip barrier split: arrive (drain stores) -> [prestage weights during the
// poll] -> wait. Monotonic counter, relaxed atomics (r5-r13 proven).
__device__ __forceinline__ void sbar_arrive(unsigned* scnt) {
  asm volatile("s_waitcnt vmcnt(0)" ::: "memory");  // all waves drain stores
  __syncthreads();
  if (threadIdx.x == 0)
    __hip_atomic_fetch_add(scnt, 1u, __ATOMIC_RELAXED, __HIP_MEMORY_SCOPE_AGENT);
}
__device__ __forceinline__ void sbar_wait(unsigned* scnt, unsigned p) {
  if (threadIdx.x == 0) {
    while (__hip_atomic_load(scnt, __ATOMIC_RELAXED, __HIP_MEMORY_SCOPE_AGENT) < p * 8u)
      __builtin_amdgcn_s_sleep(1);
  }
  __syncthreads();
  __builtin_amdgcn_sched_barrier(0);
}

__global__ __launch_bounds__(512, 2) void k_fused(
    const float* __restrict__ xg, const float* __restrict__ xtime,
    const __hip_bfloat16* __restrict__ W1t, const float* __restrict__ b1,
    const __hip_bfloat16* __restrict__ W2t, const float* __restrict__ b2,
    const __hip_bfloat16* __restrict__ Wzrt, const float* __restrict__ bz,
    const float* __restrict__ br, const __hip_bfloat16* __restrict__ Wnt,
    const float* __restrict__ bn, float* __restrict__ hf, float* __restrict__ hstdf,
    __hip_bfloat16* __restrict__ hbf, __hip_bfloat16* __restrict__ Ubf,
    __hip_bfloat16* __restrict__ hodeb, __hip_bfloat16* __restrict__ hstdb,
    __hip_bfloat16* __restrict__ A4, __hip_bfloat16* __restrict__ xstep,
    unsigned* __restrict__ bar) {
  __shared__ __align__(16) unsigned short lA[5][32 * 64];    // 20 KB, A depth-4
  __shared__ __align__(16) unsigned short lB[4][128 * 64];   // 64 KB, B depth-3
  int tid = threadIdx.x, lane = tid & 63, wv = tid >> 6;
  int lr = lane & 15, lg = lane >> 4;
  int rh = wv >> 2, cq = wv & 3;   // wave role: row-half (0/1), col-quarter
  int b = blockIdx.x;
  // strip co-location per XCD (b&7 = XCD round-robin, m09): each strip's 8
  // blocks share ONE XCD's L2 — the visibility domain for plain-store +
  // L1-inv + plain-load. [HARD dependency, declared: wrong mapping => fail]
  int xcd = b & 7;
  int j = b >> 3;
  int i = (xcd << 2) | (j >> 3);   // strip 0..31 (4 strips per XCD)
  int s = j & 7;                   // slice 0..7
  int m0 = i << 5;                 // 32-row strip
  int nA = s << 6;                 // owned 64-column base (ALL phases)
  unsigned* scnt = bar + i * 32;
  unsigned p = 0;
  // per-thread owned cell: rows m0+(rh*16)+(lg*4+r), col nA+(cq*16)+lr.
  // ALL f32 state (h, hstd, h_ode, z) lives in these registers.
  int cl = (cq << 4) + lr;
  int col = nA + cl;
  int row0 = m0 + (rh << 4) + (lg << 2);
  float hreg[4] = {0.f, 0.f, 0.f, 0.f}, sreg[4] = {0.f, 0.f, 0.f, 0.f};
  float oreg[4], zreg[4];

  // prestage P1 weight tiles 0..2
  stage512<64, 0>(W1t, H_SZ, nA, 0, lB[0], tid);
  stage512<64, 0>(W1t, H_SZ, nA, 64, lB[1], tid);
  stage512<64, 0>(W1t, H_SZ, nA, 128, lB[2], tid);

#pragma unroll 1
  for (int t = 0; t < T_SZ; ++t) {
    // ======== P1: U = tanh(h @ W1 + b1), owned cols ========
    {
      f32x4 acc = {};
      auto sa = [&](int kt, int bi) { stage512<32, AUXS>(hbf, H_SZ, m0, kt << 6, lA[bi], tid); };
      auto sb = [&](int kt, int bi) { stage512<64, 0>(W1t, H_SZ, nA, kt << 6, lB[bi], tid); };
      auto cc = [&](int ai, int bi) {
#pragma unroll
        for (int kk = 0; kk < 2; ++kk) {
          short8 a = ldfrag(lA[ai], (rh << 4) + lr, (kk << 2) + lg);
          short8 bb = ldfrag(lB[bi], cl, (kk << 2) + lg);
          acc = mfma16(a, bb, acc);
        }
      };
      gloop<8, 1>(wv, sa, sb, cc);
      float bi = b1[col];
#pragma unroll
      for (int r = 0; r < 4; ++r)
        st_bf16(&Ubf[(size_t)(row0 + r) * H_SZ + col], tanhf(acc[r] + bi));
    }
    sbar_arrive(scnt);
    stage512<64, 0>(W2t, H_SZ, nA, 0, lB[0], tid);
    stage512<64, 0>(W2t, H_SZ, nA, 64, lB[1], tid);
    stage512<64, 0>(W2t, H_SZ, nA, 128, lB[2], tid);
    sbar_wait(scnt, ++p);
    INV();  // drop stale L1 lines; fresh Ubf is in this XCD's L2
    // ======== P2: h_ode = h + dt*(U @ W2 + b2); x slice -> bf16 ========
    {
      f32x4 acc = {};
      auto sa = [&](int kt, int bi) { stage512<32, AUXS>(Ubf, H_SZ, m0, kt << 6, lA[bi], tid); };
      auto sb = [&](int kt, int bi) { stage512<64, 0>(W2t, H_SZ, nA, kt << 6, lB[bi], tid); };
      auto cc = [&](int ai, int bi) {
#pragma unroll
        for (int kk = 0; kk < 2; ++kk) {
          short8 a = ldfrag(lA[ai], (rh << 4) + lr, (kk << 2) + lg);
          short8 bb = ldfrag(lB[bi], cl, (kk << 2) + lg);
          acc = mfma16(a, bb, acc);
        }
      };
      gloop<8, 1>(wv, sa, sb, cc);
      float dtv = (t == 0) ? 0.01f : (xtime[t] - xtime[t - 1]);
      float bi = b2[col];
#pragma unroll
      for (int r = 0; r < 4; ++r) {
        float v = hreg[r] + dtv * (acc[r] + bi);
        oreg[r] = v;
        st_bf16(&hodeb[(size_t)(row0 + r) * H_SZ + col], v);
      }
      {  // x[:, t, s-slice] -> bf16 (32 strip rows, 32 cols per slice)
        int colx = (s << 5) + (tid & 31);
#pragma unroll
        for (int it2 = 0; it2 < 2; ++it2) {
          int row = m0 + (tid >> 5) + (it2 << 4);
          float xv = xg[((size_t)row * T_SZ + t) * D_SZ + colx];
          st_bf16(&xstep[(size_t)row * D_SZ + colx], xv);
        }
      }
    }
    sbar_arrive(scnt);
#pragma unroll
    for (int q = 0; q < 3; ++q) {  // prestage P3 B0..2 ([z-half | r-half])
      stage512<64, 0>(Wzrt, 1280, nA, q << 6, lB[q], tid);
      stage512<64, 0>(Wzrt, 1280, 512 + nA, q << 6, lB[q] + 64 * 64, tid);
    }
    sbar_wait(scnt, ++p);
    INV();
    // ======== P3: z,r = sigmoid(cat @ WzrT), owned cols; build A4 ========
    {
      f32x4 acc0 = {}, acc1 = {};
      auto sa = [&](int kt, int bi) {
        int ke = kt << 6;
        if (ke < 512)       stage512<32, AUXS>(hodeb, H_SZ, m0, ke, lA[bi], tid);
        else if (ke < 1024) stage512<32, AUXS>(hstdb, H_SZ, m0, ke - 512, lA[bi], tid);
        else                stage512<32, AUXS>(xstep, D_SZ, m0, ke - 1024, lA[bi], tid);
      };
      auto sb = [&](int kt, int bi) {
        stage512<64, 0>(Wzrt, 1280, nA, kt << 6, lB[bi], tid);
        stage512<64, 0>(Wzrt, 1280, 512 + nA, kt << 6, lB[bi] + 64 * 64, tid);
      };
      auto cc = [&](int ai, int bi) {
#pragma unroll
        for (int kk = 0; kk < 2; ++kk) {
          short8 a = ldfrag(lA[ai], (rh << 4) + lr, (kk << 2) + lg);
          short8 b0 = ldfrag(lB[bi], cl, (kk << 2) + lg);          // z-cols
          short8 b1f = ldfrag(lB[bi], 64 + cl, (kk << 2) + lg);    // r-cols
          acc0 = mfma16(a, b0, acc0);
          acc1 = mfma16(a, b1f, acc1);
        }
      };
      gloop<20, 2>(wv, sa, sb, cc);
      float bz_ = bz[col], br_ = br[col];
#pragma unroll
      for (int r = 0; r < 4; ++r) {
        int row = row0 + r;
        zreg[r] = 1.f / (1.f + expf(-(acc0[r] + bz_)));
        float g = 1.f / (1.f + expf(-(acc1[r] + br_)));
        st_bf16(&A4[(size_t)row * 1024 + col], oreg[r] * g);
        st_bf16(&A4[(size_t)row * 1024 + 512 + col], sreg[r] * g);
      }
    }
    sbar_arrive(scnt);
#pragma unroll
    for (int q = 0; q < 3; ++q) {  // prestage P4 B0..2 ([mean | std])
      stage512<64, 0>(Wnt, 1280, nA, q << 6, lB[q], tid);
      stage512<64, 0>(Wnt, 1280, 512 + nA, q << 6, lB[q] + 64 * 64, tid);
    }
    sbar_wait(scnt, ++p);
    INV();
    // ======== P4: n_mean,n_std owned cols; GRU update in registers ========
    {
      f32x4 acc0 = {}, acc1 = {};
      auto sa = [&](int kt, int bi) {
        int ke = kt << 6;
        if (ke < 1024) stage512<32, AUXS>(A4, 1024, m0, ke, lA[bi], tid);
        else           stage512<32, AUXS>(xstep, D_SZ, m0, ke - 1024, lA[bi], tid);
      };
      auto sb = [&](int kt, int bi) {
        stage512<64, 0>(Wnt, 1280, nA, kt << 6, lB[bi], tid);
        stage512<64, 0>(Wnt, 1280, 512 + nA, kt << 6, lB[bi] + 64 * 64, tid);
      };
      auto cc = [&](int ai, int bi) {
#pragma unroll
        for (int kk = 0; kk < 2; ++kk) {
          short8 a = ldfrag(lA[ai], (rh << 4) + lr, (kk << 2) + lg);
          short8 b0 = ldfrag(lB[bi], cl, (kk << 2) + lg);          // mean
          short8 b1f = ldfrag(lB[bi], 64 + cl, (kk << 2) + lg);    // std
          acc0 = mfma16(a, b0, acc0);
          acc1 = mfma16(a, b1f, acc1);
        }
      };
      gloop<20, 2>(wv, sa, sb, cc);
      float bm = bn[col], bs = bn[512 + col];
#pragma unroll
      for (int r = 0; r < 4; ++r) {
        int row = row0 + r;
        float z = zreg[r];
        float hn = (1.f - z) * (acc0[r] + bm) + z * oreg[r];
        hreg[r] = hn;
        st_bf16(&hbf[(size_t)row * H_SZ + col], hn);
        float ns = fabsf(acc1[r] + bs);
        float sn = fabsf((1.f - z) * ns + z * sreg[r]);
        sreg[r] = sn;
        st_bf16(&hstdb[(size_t)row * H_SZ + col], sn);
      }
    }
    sbar_arrive(scnt);
    stage512<64, 0>(W1t, H_SZ, nA, 0, lB[0], tid);   // prestage next P1 B0..2
    stage512<64, 0>(W1t, H_SZ, nA, 64, lB[1], tid);
    stage512<64, 0>(W1t, H_SZ, nA, 128, lB[2], tid);
    sbar_wait(scnt, ++p);
    INV();
  }
  // final output: register state -> global
#pragma unroll
  for (int r = 0; r < 4; ++r) {
    int row = row0 + r;
    hf[(size_t)row * H_SZ + col] = hreg[r];
    hstdf[(size_t)row * H_SZ + col] = sreg[r];
  }
}

// =============== prep: W[k][n] f32  ->  Wt[n][k] bf16 =====================
__global__ void k_wt(const float* __restrict__ W, __hip_bfloat16* __restrict__ Wt,
                     int K, int N, int ld) {
  size_t i = (size_t)blockIdx.x * 256 + threadIdx.x;
  if (i >= (size_t)K * N) return;
  int n = (int)(i / K), k = (int)(i % K);
  Wt[(size_t)n * ld + k] = __float2bfloat16(W[(size_t)k * N + n]);
}

extern "C" void kernel_launch(void* const* d_in, const int* in_sizes, int n_in,
                              void* d_out, int out_size, void* d_ws, size_t ws_size,
                              hipStream_t stream) {
  const float* x     = (const float*)d_in[0];
  const float* xtime = (const float*)d_in[1];
  const float* W1    = (const float*)d_in[2];
  const float* b1    = (const float*)d_in[3];
  const float* W2    = (const float*)d_in[4];
  const float* b2    = (const float*)d_in[5];
  const float* Wz    = (const float*)d_in[6];
  const float* bz    = (const float*)d_in[7];
  const float* Wr    = (const float*)d_in[8];
  const float* br    = (const float*)d_in[9];
  const float* Wn    = (const float*)d_in[10];
  const float* bn    = (const float*)d_in[11];

  char* p = (char*)d_ws;
  __hip_bfloat16* W1t   = (__hip_bfloat16*)(p + 0);
  __hip_bfloat16* W2t   = (__hip_bfloat16*)(p + 524288);
  __hip_bfloat16* Wzrt  = (__hip_bfloat16*)(p + 1048576);
  __hip_bfloat16* Wnt   = (__hip_bfloat16*)(p + 3670016);
  float*          hf    = (float*)(p + 6291456);
  float*          hstdf = (float*)(p + 8388608);
  __hip_bfloat16* hbf   = (__hip_bfloat16*)(p + 14680064);
  __hip_bfloat16* Ubf   = (__hip_bfloat16*)(p + 15728640);
  __hip_bfloat16* hodeb = (__hip_bfloat16*)(p + 16777216);
  __hip_bfloat16* hstdb = (__hip_bfloat16*)(p + 17825792);
  __hip_bfloat16* A4    = (__hip_bfloat16*)(p + 18874368);
  __hip_bfloat16* xstep = (__hip_bfloat16*)(p + 20971520);
  unsigned*       bar   = (unsigned*)(p + 21495808);

  hipMemsetAsync(hbf, 0, 1048576, stream);
  hipMemsetAsync(hstdb, 0, 1048576, stream);
  hipMemsetAsync(bar, 0, 8192, stream);

  k_wt<<<(512 * 512 + 255) / 256, 256, 0, stream>>>(W1, W1t, 512, 512, 512);
  k_wt<<<(512 * 512 + 255) / 256, 256, 0, stream>>>(W2, W2t, 512, 512, 512);
  k_wt<<<(1280 * 512 + 255) / 256, 256, 0, stream>>>(Wz, Wzrt, 1280, 512, 1280);
  k_wt<<<(1280 * 512 + 255) / 256, 256, 0, stream>>>(Wr, Wzrt + (size_t)512 * 1280, 1280, 512, 1280);
  k_wt<<<(1280 * 1024 + 255) / 256, 256, 0, stream>>>(Wn, Wnt, 1280, 1024, 1280);

  // persistent kernel: r13-best structure; state via plain stores (write-
  // through L1 -> XCD L2) + per-CU L1 invalidate + plain cached loads —
  // state reads become same-XCD L2 hits instead of HBM round-trips
  k_fused<<<NBLK, NTHR, 0, stream>>>(x, xtime, W1t, b1, W2t, b2, Wzrt, bz, br,
                                     Wnt, bn, hf, hstdf, hbf, Ubf,
                                     hodeb, hstdb, A4, xstep, bar);

  hipMemcpyAsync(d_out, hf, 2097152, hipMemcpyDeviceToDevice, stream);
  hipMemcpyAsync((char*)d_out + 2097152, hstdf, 2097152, hipMemcpyDeviceToDevice, stream);
}

// Round 21
// 4165.093 us; speedup vs baseline: 12.6272x; 1.1958x over previous
//
#include <hip/hip_runtime.h>
#include <hip/hip_bf16.h>

#define B_SZ 1024
#define T_SZ 128
#define D_SZ 256
#define H_SZ 512
#define NBLK 256
#define NTHR 512

typedef __attribute__((ext_vector_type(8))) short short8;
typedef __attribute__((ext_vector_type(4))) float f32x4;

__device__ inline f32x4 mfma16(short8 a, short8 b, f32x4 c) {
  return __builtin_amdgcn_mfma_f32_16x16x32_bf16(a, b, c, 0, 0, 0);
}

// plain write-back state store: write-through L1 -> this XCD's L2 (strip
// blocks co-located), retired by vmcnt(0) before the strip barrier signals.
__device__ inline void st_bf16(__hip_bfloat16* p, float v) {
  union { __hip_bfloat16 b; unsigned short u; } cv;
  cv.b = __float2bfloat16(v);
  unsigned int vv = cv.u;
  asm volatile("global_store_short %0, %1, off" :: "v"(p), "v"(vv) : "memory");
}

// per-CU vector-L1 invalidate (sc0 = L1 scope only) — readers then see the
// XCD-L2's fresh state via plain cached loads.
#define INV()                                        \
  do {                                               \
    asm volatile("buffer_inv sc0" ::: "memory");     \
    __builtin_amdgcn_sched_barrier(0);               \
  } while (0)

// Stage ROWS x 128 bf16 tile -> LDS [ROWS][128], slot-swizzled: 16B slot s of
// row r holds k-slot s^(r&7) (XOR on low 3 bits); linear LDS dest +
// inverse-swizzled global source. ROWS=32 -> 1 instr/thread (all 8 waves);
// ROWS=64 -> 2 instrs/thread.
template <int ROWS, int AUX>
__device__ __forceinline__ void stageW(const __hip_bfloat16* __restrict__ src,
                                       int strideElts, int row0, int k0,
                                       unsigned short* lds, int tid) {
  constexpr int CH = ROWS * 16;   // 16B chunks (16 per 128-col row)
#pragma unroll
  for (int it = 0; it * NTHR < CH; ++it) {
    int wbase = it * NTHR + ((tid >> 6) << 6);
    if (wbase < CH) {
      int chunk = it * NTHR + tid;
      int row = chunk >> 4, sl = chunk & 15;
      int ksrc = (sl ^ (row & 7)) << 3;
      const __hip_bfloat16* g = src + (size_t)(row0 + row) * strideElts + (k0 + ksrc);
      unsigned short* l = lds + (size_t)wbase * 8;
      __builtin_amdgcn_global_load_lds(
          (const __attribute__((address_space(1))) unsigned int*)g,
          (__attribute__((address_space(3))) unsigned int*)l, 16, 0, AUX);
    }
  }
}

// read a 16B fragment from a [*][128] tile with matching swizzle (slot 0..15)
__device__ __forceinline__ short8 ldf(const unsigned short* buf, int row, int slot) {
  int s = slot ^ (row & 7);
  return *(const short8*)(buf + row * 128 + (s << 3));
}

// Counted-vmcnt mainloop, BK=128. A depth-4 (5 buffers, tiles 0..3 issued at
// entry, 1 instr per wave per tile), B depth-2+prestage (3 buffers, B0,B1
// prestaged before the strip barrier, PB instrs per wave per tile).
// Per-iter order: wait, barrier, sb(kt+2), sa(kt+4), cc(kt).
// In-order vmcnt (all waves issue identically):
//  kt=0: force A0 (B0 older)            -> vmcnt(3)
//  kt=1: force A1; younger = A2,A3,B2[,A5 if NT>4... A-issue kt+4]
//        -> vmcnt(2+PB + (NT>4 ? 1 : 0))
//  2..NT-4: force B[kt]; younger = A[kt+2],A[kt+3],B[kt+1] -> vmcnt(2+PB)
//  NT-3: vmcnt(1+PB);  NT-2: vmcnt(PB);  NT-1: vmcnt(0)
template <int NT, int PB, typename SA, typename SB, typename CC>
__device__ __forceinline__ void gloop(SA sa, SB sb, CC cc) {
  sa(0, 0); sa(1, 1); sa(2, 2); sa(3, 3);
#pragma unroll 1
  for (int kt = 0; kt < NT; ++kt) {
    if (kt == 0)           asm volatile("s_waitcnt vmcnt(3)" ::: "memory");
    else if (kt == 1)      asm volatile("s_waitcnt vmcnt(%0)" :: "i"(2 + PB + (NT > 4 ? 1 : 0)) : "memory");
    else if (kt <= NT - 4) asm volatile("s_waitcnt vmcnt(%0)" :: "i"(2 + PB) : "memory");
    else if (kt == NT - 3) asm volatile("s_waitcnt vmcnt(%0)" :: "i"(1 + PB) : "memory");
    else if (kt == NT - 2) asm volatile("s_waitcnt vmcnt(%0)" :: "i"(PB) : "memory");
    else                   asm volatile("s_waitcnt vmcnt(0)" ::: "memory");
    __builtin_amdgcn_s_barrier();
    __builtin_amdgcn_sched_barrier(0);
    if (kt + 2 < NT) sb(kt + 2, (kt + 2) % 3);
    if (kt + 4 < NT) sa(kt + 4, (kt + 4) % 5);
    cc(kt % 5, kt % 3);
  }
}

// Strip barrier split: arrive (drain stores) -> prestage next-phase B0,B1
// during the poll -> wait. Monotonic counter, relaxed atomics.
__device__ __forceinline__ void sbar_arrive(unsigned* scnt) {
  asm volatile("s_waitcnt vmcnt(0)" ::: "memory");
  __syncthreads();
  if (threadIdx.x == 0)
    __hip_atomic_fetch_add(scnt, 1u, __ATOMIC_RELAXED, __HIP_MEMORY_SCOPE_AGENT);
}
__device__ __forceinline__ void sbar_wait(unsigned* scnt, unsigned p) {
  if (threadIdx.x == 0) {
    while (__hip_atomic_load(scnt, __ATOMIC_RELAXED, __HIP_MEMORY_SCOPE_AGENT) < p * 8u)
      __builtin_amdgcn_s_sleep(1);
  }
  __syncthreads();
  __builtin_amdgcn_sched_barrier(0);
}

__global__ __launch_bounds__(512, 1) void k_fused(
    const float* __restrict__ xg, const float* __restrict__ xtime,
    const __hip_bfloat16* __restrict__ W1t, const float* __restrict__ b1,
    const __hip_bfloat16* __restrict__ W2t, const float* __restrict__ b2,
    const __hip_bfloat16* __restrict__ Wzrt, const float* __restrict__ bz,
    const float* __restrict__ br, const __hip_bfloat16* __restrict__ Wnt,
    const float* __restrict__ bn, float* __restrict__ hf, float* __restrict__ hstdf,
    __hip_bfloat16* __restrict__ hbf, __hip_bfloat16* __restrict__ Ubf,
    __hip_bfloat16* __restrict__ hodeb, __hip_bfloat16* __restrict__ hstdb,
    __hip_bfloat16* __restrict__ A4, __hip_bfloat16* __restrict__ xstep,
    unsigned* __restrict__ bar) {
  __shared__ __align__(16) unsigned short lA[5][32 * 128];    // 40 KB, A depth-4
  __shared__ __align__(16) unsigned short lB[3][128 * 128];   // 96 KB, B 3 bufs
  int tid = threadIdx.x, lane = tid & 63, wv = tid >> 6;
  int lr = lane & 15, lg = lane >> 4;
  int rh = wv >> 2, cq = wv & 3;   // wave role: row-half (0/1), col-quarter
  int b = blockIdx.x;
  // strip co-location per XCD (b&7 = XCD round-robin): each strip's 8 blocks
  // share ONE XCD's L2 — visibility domain for plain-store + L1-inv + load.
  int xcd = b & 7;
  int j = b >> 3;
  int i = (xcd << 2) | (j >> 3);   // strip 0..31 (4 strips per XCD)
  int s = j & 7;                   // slice 0..7
  int m0 = i << 5;                 // 32-row strip
  int nA = s << 6;                 // owned 64-column base (ALL phases)
  unsigned* scnt = bar + i * 32;
  unsigned p = 0;
  int cl = (cq << 4) + lr;
  int col = nA + cl;
  int row0 = m0 + (rh << 4) + (lg << 2);
  float hreg[4] = {0.f, 0.f, 0.f, 0.f}, sreg[4] = {0.f, 0.f, 0.f, 0.f};
  float oreg[4], zreg[4];

  INV();  // drop any stale L1 lines from a previous graph replay
  // prestage P1 B0,B1
  stageW<64, 0>(W1t, H_SZ, nA, 0, lB[0], tid);
  stageW<64, 0>(W1t, H_SZ, nA, 128, lB[1], tid);

#pragma unroll 1
  for (int t = 0; t < T_SZ; ++t) {
    // ======== P1: U = tanh(h @ W1 + b1), owned cols (NT=4, PB=2) ========
    {
      f32x4 acc = {};
      auto sa = [&](int kt, int bi) { stageW<32, 0>(hbf, H_SZ, m0, kt << 7, lA[bi], tid); };
      auto sb = [&](int kt, int bi) { stageW<64, 0>(W1t, H_SZ, nA, kt << 7, lB[bi], tid); };
      auto cc = [&](int ai, int bi) {
#pragma unroll
        for (int kk = 0; kk < 4; ++kk) {
          short8 a = ldf(lA[ai], (rh << 4) + lr, (kk << 2) + lg);
          short8 bb = ldf(lB[bi], cl, (kk << 2) + lg);
          acc = mfma16(a, bb, acc);
        }
      };
      gloop<4, 2>(sa, sb, cc);
      float bi = b1[col];
#pragma unroll
      for (int r = 0; r < 4; ++r)
        st_bf16(&Ubf[(size_t)(row0 + r) * H_SZ + col], tanhf(acc[r] + bi));
    }
    sbar_arrive(scnt);
    stageW<64, 0>(W2t, H_SZ, nA, 0, lB[0], tid);
    stageW<64, 0>(W2t, H_SZ, nA, 128, lB[1], tid);
    sbar_wait(scnt, ++p);
    INV();
    // ======== P2: h_ode = h + dt*(U @ W2 + b2); x -> bf16 (NT=4, PB=2) ======
    {
      f32x4 acc = {};
      auto sa = [&](int kt, int bi) { stageW<32, 0>(Ubf, H_SZ, m0, kt << 7, lA[bi], tid); };
      auto sb = [&](int kt, int bi) { stageW<64, 0>(W2t, H_SZ, nA, kt << 7, lB[bi], tid); };
      auto cc = [&](int ai, int bi) {
#pragma unroll
        for (int kk = 0; kk < 4; ++kk) {
          short8 a = ldf(lA[ai], (rh << 4) + lr, (kk << 2) + lg);
          short8 bb = ldf(lB[bi], cl, (kk << 2) + lg);
          acc = mfma16(a, bb, acc);
        }
      };
      gloop<4, 2>(sa, sb, cc);
      float dtv = (t == 0) ? 0.01f : (xtime[t] - xtime[t - 1]);
      float bi = b2[col];
#pragma unroll
      for (int r = 0; r < 4; ++r) {
        float v = hreg[r] + dtv * (acc[r] + bi);
        oreg[r] = v;
        st_bf16(&hodeb[(size_t)(row0 + r) * H_SZ + col], v);
      }
      {  // x[:, t, s-slice] -> bf16 (32 strip rows, 32 cols per slice)
        int colx = (s << 5) + (tid & 31);
#pragma unroll
        for (int it2 = 0; it2 < 2; ++it2) {
          int row = m0 + (tid >> 5) + (it2 << 4);
          float xv = xg[((size_t)row * T_SZ + t) * D_SZ + colx];
          st_bf16(&xstep[(size_t)row * D_SZ + colx], xv);
        }
      }
    }
    sbar_arrive(scnt);
#pragma unroll
    for (int q = 0; q < 2; ++q) {  // prestage P3 B0,B1 ([z-half | r-half])
      stageW<64, 0>(Wzrt, 1280, nA, q << 7, lB[q], tid);
      stageW<64, 0>(Wzrt, 1280, 512 + nA, q << 7, lB[q] + 64 * 128, tid);
    }
    sbar_wait(scnt, ++p);
    INV();
    // ======== P3: z,r = sigmoid(cat @ WzrT); build A4 (NT=10, PB=4) ========
    {
      f32x4 acc0 = {}, acc1 = {};
      auto sa = [&](int kt, int bi) {
        int ke = kt << 7;
        if (ke < 512)       stageW<32, 0>(hodeb, H_SZ, m0, ke, lA[bi], tid);
        else if (ke < 1024) stageW<32, 0>(hstdb, H_SZ, m0, ke - 512, lA[bi], tid);
        else                stageW<32, 0>(xstep, D_SZ, m0, ke - 1024, lA[bi], tid);
      };
      auto sb = [&](int kt, int bi) {
        stageW<64, 0>(Wzrt, 1280, nA, kt << 7, lB[bi], tid);
        stageW<64, 0>(Wzrt, 1280, 512 + nA, kt << 7, lB[bi] + 64 * 128, tid);
      };
      auto cc = [&](int ai, int bi) {
#pragma unroll
        for (int kk = 0; kk < 4; ++kk) {
          short8 a = ldf(lA[ai], (rh << 4) + lr, (kk << 2) + lg);
          short8 b0 = ldf(lB[bi], cl, (kk << 2) + lg);              // z-cols
          short8 b1f = ldf(lB[bi] + 64 * 128, cl, (kk << 2) + lg);  // r-cols
          acc0 = mfma16(a, b0, acc0);
          acc1 = mfma16(a, b1f, acc1);
        }
      };
      gloop<10, 4>(sa, sb, cc);
      float bz_ = bz[col], br_ = br[col];
#pragma unroll
      for (int r = 0; r < 4; ++r) {
        int row = row0 + r;
        zreg[r] = 1.f / (1.f + expf(-(acc0[r] + bz_)));
        float g = 1.f / (1.f + expf(-(acc1[r] + br_)));
        st_bf16(&A4[(size_t)row * 1024 + col], oreg[r] * g);
        st_bf16(&A4[(size_t)row * 1024 + 512 + col], sreg[r] * g);
      }
    }
    sbar_arrive(scnt);
#pragma unroll
    for (int q = 0; q < 2; ++q) {  // prestage P4 B0,B1 ([mean | std])
      stageW<64, 0>(Wnt, 1280, nA, q << 7, lB[q], tid);
      stageW<64, 0>(Wnt, 1280, 512 + nA, q << 7, lB[q] + 64 * 128, tid);
    }
    sbar_wait(scnt, ++p);
    INV();
    // ======== P4: n_mean,n_std; GRU update in registers (NT=10, PB=4) ======
    {
      f32x4 acc0 = {}, acc1 = {};
      auto sa = [&](int kt, int bi) {
        int ke = kt << 7;
        if (ke < 1024) stageW<32, 0>(A4, 1024, m0, ke, lA[bi], tid);
        else           stageW<32, 0>(xstep, D_SZ, m0, ke - 1024, lA[bi], tid);
      };
      auto sb = [&](int kt, int bi) {
        stageW<64, 0>(Wnt, 1280, nA, kt << 7, lB[bi], tid);
        stageW<64, 0>(Wnt, 1280, 512 + nA, kt << 7, lB[bi] + 64 * 128, tid);
      };
      auto cc = [&](int ai, int bi) {
#pragma unroll
        for (int kk = 0; kk < 4; ++kk) {
          short8 a = ldf(lA[ai], (rh << 4) + lr, (kk << 2) + lg);
          short8 b0 = ldf(lB[bi], cl, (kk << 2) + lg);              // mean
          short8 b1f = ldf(lB[bi] + 64 * 128, cl, (kk << 2) + lg);  // std
          acc0 = mfma16(a, b0, acc0);
          acc1 = mfma16(a, b1f, acc1);
        }
      };
      gloop<10, 4>(sa, sb, cc);
      float bm = bn[col], bs = bn[512 + col];
#pragma unroll
      for (int r = 0; r < 4; ++r) {
        int row = row0 + r;
        float z = zreg[r];
        float hn = (1.f - z) * (acc0[r] + bm) + z * oreg[r];
        hreg[r] = hn;
        st_bf16(&hbf[(size_t)row * H_SZ + col], hn);
        float ns = fabsf(acc1[r] + bs);
        float sn = fabsf((1.f - z) * ns + z * sreg[r]);
        sreg[r] = sn;
        st_bf16(&hstdb[(size_t)row * H_SZ + col], sn);
      }
    }
    sbar_arrive(scnt);
    stageW<64, 0>(W1t, H_SZ, nA, 0, lB[0], tid);   // prestage next P1 B0,B1
    stageW<64, 0>(W1t, H_SZ, nA, 128, lB[1], tid);
    sbar_wait(scnt, ++p);
    INV();
  }
  // final output: register state -> global
#pragma unroll
  for (int r = 0; r < 4; ++r) {
    int row = row0 + r;
    hf[(size_t)row * H_SZ + col] = hreg[r];
    hstdf[(size_t)row * H_SZ + col] = sreg[r];
  }
}

// =============== prep: W[k][n] f32  ->  Wt[n][k] bf16 =====================
__global__ void k_wt(const float* __restrict__ W, __hip_bfloat16* __restrict__ Wt,
                     int K, int N, int ld) {
  size_t i = (size_t)blockIdx.x * 256 + threadIdx.x;
  if (i >= (size_t)K * N) return;
  int n = (int)(i / K), k = (int)(i % K);
  Wt[(size_t)n * ld + k] = __float2bfloat16(W[(size_t)k * N + n]);
}

extern "C" void kernel_launch(void* const* d_in, const int* in_sizes, int n_in,
                              void* d_out, int out_size, void* d_ws, size_t ws_size,
                              hipStream_t stream) {
  const float* x     = (const float*)d_in[0];
  const float* xtime = (const float*)d_in[1];
  const float* W1    = (const float*)d_in[2];
  const float* b1    = (const float*)d_in[3];
  const float* W2    = (const float*)d_in[4];
  const float* b2    = (const float*)d_in[5];
  const float* Wz    = (const float*)d_in[6];
  const float* bz    = (const float*)d_in[7];
  const float* Wr    = (const float*)d_in[8];
  const float* br    = (const float*)d_in[9];
  const float* Wn    = (const float*)d_in[10];
  const float* bn    = (const float*)d_in[11];

  char* p = (char*)d_ws;
  __hip_bfloat16* W1t   = (__hip_bfloat16*)(p + 0);
  __hip_bfloat16* W2t   = (__hip_bfloat16*)(p + 524288);
  __hip_bfloat16* Wzrt  = (__hip_bfloat16*)(p + 1048576);
  __hip_bfloat16* Wnt   = (__hip_bfloat16*)(p + 3670016);
  float*          hf    = (float*)(p + 6291456);
  float*          hstdf = (float*)(p + 8388608);
  __hip_bfloat16* hbf   = (__hip_bfloat16*)(p + 14680064);
  __hip_bfloat16* Ubf   = (__hip_bfloat16*)(p + 15728640);
  __hip_bfloat16* hodeb = (__hip_bfloat16*)(p + 16777216);
  __hip_bfloat16* hstdb = (__hip_bfloat16*)(p + 17825792);
  __hip_bfloat16* A4    = (__hip_bfloat16*)(p + 18874368);
  __hip_bfloat16* xstep = (__hip_bfloat16*)(p + 20971520);
  unsigned*       bar   = (unsigned*)(p + 21495808);

  hipMemsetAsync(hbf, 0, 1048576, stream);
  hipMemsetAsync(hstdb, 0, 1048576, stream);
  hipMemsetAsync(bar, 0, 8192, stream);

  k_wt<<<(512 * 512 + 255) / 256, 256, 0, stream>>>(W1, W1t, 512, 512, 512);
  k_wt<<<(512 * 512 + 255) / 256, 256, 0, stream>>>(W2, W2t, 512, 512, 512);
  k_wt<<<(1280 * 512 + 255) / 256, 256, 0, stream>>>(Wz, Wzrt, 1280, 512, 1280);
  k_wt<<<(1280 * 512 + 255) / 256, 256, 0, stream>>>(Wr, Wzrt + (size_t)512 * 1280, 1280, 512, 1280);
  k_wt<<<(1280 * 1024 + 255) / 256, 256, 0, stream>>>(Wn, Wnt, 1280, 1024, 1280);

  // persistent kernel: r20 structure with BK=128 — 28 k-iterations/step
  // (was 56), 2x MFMA per barrier-iteration, same sync/coherence scheme
  k_fused<<<NBLK, NTHR, 0, stream>>>(x, xtime, W1t, b1, W2t, b2, Wzrt, bz, br,
                                     Wnt, bn, hf, hstdf, hbf, Ubf,
                                     hodeb, hstdb, A4, xstep, bar);

  hipMemcpyAsync(d_out, hf, 2097152, hipMemcpyDeviceToDevice, stream);
  hipMemcpyAsync((char*)d_out + 2097152, hstdf, 2097152, hipMemcpyDeviceToDevice, stream);
}